// Round 3
// baseline (210.444 us; speedup 1.0000x reference)
//
#include <hip/hip_runtime.h>
#include <hip/hip_bf16.h>

// InnocentAttention: B=4 H=16 S=2048 D=64, fp32 in/out, per-batch event_length mask.
//
// R8: prepass now emits K/V tiles in FRAGMENT-ORDERED global layout: per 64-key
// tile, 16 lines of 1KB; line fi at byte lane*16 is exactly the 16B MFMA fragment
// for lane (K lines: [mt][half]; V lines: [kc][dt], pi key-permutation baked in).
// Main kernel is wave-independent: NO LDS, NO barriers, NO DMA -- each wave pulls
// a 32-query item from a global ticket queue and reads fragments directly from
// global (coalesced dwordx4, L2/L3-resident 32MB working set). Kills the
// per-tile vmcnt(0)+__syncthreads lockstep that capped R6/R7 at ~13% MfmaUtil.
// Falls back to the proven R5 path when ws_size < ~33.6 MB.

#define SQ 2048
#define DH 64
#define NBH 64
#define TK 64
#define NTILE 32           // SQ / TK
#define TILE_B 8192        // TK * DH * 2 bytes (bf16)
#define LDE 72             // fallback-path padded LDS stride
#define LVP 68             // prepass V-stage stride (2-way max conflicts)

typedef __attribute__((ext_vector_type(4))) float f32x4;
typedef __attribute__((ext_vector_type(8))) short bf16x8;
typedef __attribute__((ext_vector_type(4))) unsigned int u32x4;
typedef __attribute__((ext_vector_type(2))) unsigned int u32x2;

__device__ __forceinline__ unsigned int pk2(float lo, float hi) {
    // v_cvt_pk_bf16_f32 on gfx950 (RNE), lo -> low 16 bits
    __hip_bfloat162 h = __float22bfloat162_rn(float2{lo, hi});
    union { __hip_bfloat162 h; unsigned int u; } c; c.h = h;
    return c.u;
}

__device__ __forceinline__ float bfu16_to_f(unsigned short s) {
    union { unsigned int u; float f; } c; c.u = ((unsigned int)s) << 16;
    return c.f;
}

// ============================================================================
// NEW PATH
// ============================================================================

// Prepass: one block per (bh, 64-key tile). Fragment-ordered output:
//  K tile: line fi = mt*2+half (1KB each); lane l=(qd*16+c) 16B =
//          K[key=mt*16+c][d = half*32+qd*8 .. +7] bf16.
//  V tile: line fi = kc*4+dt; lane l=(qd*16+c) 16B, element j =
//          V[key = kc*32 + (j>>2)*16 + qd*4 + (j&3)][d = dt*16+c]  (pi order)
//  MV[bh][d] += mean contribution of this tile's 64 V rows (atomic)
__global__ __launch_bounds__(256)
void convkv(const float* __restrict__ K, const float* __restrict__ V,
            const int* __restrict__ EL, float* __restrict__ MV,
            char* __restrict__ Kbt, char* __restrict__ Vbt) {
    const int bh = blockIdx.x >> 5;
    const int kt = blockIdx.x & 31;
    const int k0 = kt * TK;
    const int el = EL[bh >> 4];
    const int t = threadIdx.x;
    const int r  = t >> 2;      // key row 0..63
    const int dc = t & 3;       // 16-d chunk

    __shared__ short LV[64][LVP];

    // stage V row (bf16) into LDS for transpose + mean
    {
        const float* vp = V + ((size_t)bh * SQ + k0 + r) * DH + dc * 16;
        f32x4 a = *(const f32x4*)vp;
        f32x4 b = *(const f32x4*)(vp + 4);
        f32x4 c2 = *(const f32x4*)(vp + 8);
        f32x4 d2 = *(const f32x4*)(vp + 12);
        u32x4 w0, w1;
        w0[0] = pk2(a[0], a[1]);  w0[1] = pk2(a[2], a[3]);
        w0[2] = pk2(b[0], b[1]);  w0[3] = pk2(b[2], b[3]);
        w1[0] = pk2(c2[0], c2[1]); w1[1] = pk2(c2[2], c2[3]);
        w1[2] = pk2(d2[0], d2[1]); w1[3] = pk2(d2[2], d2[3]);
        *(u32x4*)&LV[r][dc * 16]     = w0;
        *(u32x4*)&LV[r][dc * 16 + 8] = w1;
    }

    // K convert (valid tiles only) -> fragment-ordered lines
    if (k0 < el) {
        const float* kp = K + ((size_t)bh * SQ + k0 + r) * DH + dc * 16;
        f32x4 a = *(const f32x4*)kp;
        f32x4 b = *(const f32x4*)(kp + 4);
        f32x4 c2 = *(const f32x4*)(kp + 8);
        f32x4 d2 = *(const f32x4*)(kp + 12);
        u32x4 w0, w1;
        w0[0] = pk2(a[0], a[1]);  w0[1] = pk2(a[2], a[3]);
        w0[2] = pk2(b[0], b[1]);  w0[3] = pk2(b[2], b[3]);
        w1[0] = pk2(c2[0], c2[1]); w1[1] = pk2(c2[2], c2[3]);
        w1[2] = pk2(d2[0], d2[1]); w1[3] = pk2(d2[2], d2[3]);
        // w0 = d-group h8 = dc*2 (half = dc>>1, qd = (dc&1)*2); w1 = qd+1
        char* kb = Kbt + (size_t)(bh * NTILE + kt) * TILE_B;
        const int fi  = (r >> 4) * 2 + (dc >> 1);
        const int qd0 = (dc & 1) * 2;
        char* d0 = kb + fi * 1024 + qd0 * 256 + (r & 15) * 16;
        *(u32x4*)d0         = w0;
        *(u32x4*)(d0 + 256) = w1;
    }

    __syncthreads();

    // transpose-read V in pi order + mean partial
    const int dd  = t >> 2;     // d row 0..63
    const int seg = t & 3;      // 16-pos segment
    float msum = 0.f;
    unsigned int wv[8];
    #pragma unroll
    for (int i = 0; i < 8; ++i) {
        const int pos = seg * 16 + 2 * i;
        const int key = (pos & ~31) | ((pos & 4) << 2) | ((pos & 24) >> 1) | (pos & 3);
        const unsigned short s0 = (unsigned short)LV[key][dd];
        const unsigned short s1 = (unsigned short)LV[key + 1][dd];
        msum += bfu16_to_f(s0) + bfu16_to_f(s1);
        wv[i] = (unsigned int)s0 | ((unsigned int)s1 << 16);
    }
    msum += __shfl_xor(msum, 1);
    msum += __shfl_xor(msum, 2);
    if (seg == 0) atomicAdd(&MV[bh * DH + dd], msum * (1.0f / (float)SQ));

    if (k0 < el) {
        // o0 = pos-group g=seg*2 (kc = seg>>1, qd = (seg&1)*2); o1 = qd+1
        char* vbb = Vbt + (size_t)(bh * NTILE + kt) * TILE_B;
        const int fi  = (seg >> 1) * 4 + (dd >> 4);
        const int qd0 = (seg & 1) * 2;
        char* d0 = vbb + fi * 1024 + qd0 * 256 + (dd & 15) * 16;
        u32x4 o0 = {wv[0], wv[1], wv[2], wv[3]};
        u32x4 o1 = {wv[4], wv[5], wv[6], wv[7]};
        *(u32x4*)d0         = o0;
        *(u32x4*)(d0 + 256) = o1;
    }
}

// Main kernel: 256 threads = 4 FULLY INDEPENDENT waves; each wave pulls
// 32-query items from a global ticket queue. No LDS, no __syncthreads.
__global__ __launch_bounds__(256, 3)
void flash8(const float* __restrict__ Q, const int* __restrict__ EL,
            const float* __restrict__ MV, float* __restrict__ O,
            const char* __restrict__ Kbt, const char* __restrict__ Vbt,
            int* __restrict__ ticket) {
    const int t = threadIdx.x;

    // ---------- static phase: mean(V) rows for own masked q-region ----------
    // Items cover rows < 32*ceil(el/32); static covers rows >= that (32-granular).
    {
        const int bh0 = blockIdx.x & (NBH - 1);
        const int qb0 = (blockIdx.x >> 6) * 128;
        const int el32b = (EL[bh0 >> 4] + 31) & ~31;
        if (qb0 + 127 >= el32b) {
            float* Op = O + (size_t)bh0 * SQ * DH;
            const int c16 = t & 15, r0 = t >> 4;
            f32x4 mv = *(const f32x4*)(MV + bh0 * DH + c16 * 4);
            #pragma unroll
            for (int i = 0; i < 8; ++i) {
                const int row = qb0 + r0 + i * 16;
                if (row >= el32b)
                    *(f32x4*)(Op + (size_t)row * DH + c16 * 4) = mv;
            }
        }
    }

    // ---------- dynamic phase: per-WAVE ticket pull over 32-q items ----------
    const int el0 = EL[0], el1 = EL[1], el2 = EL[2], el3 = EL[3];
    const int w0_ = (el0 + 31) >> 5, w1_ = (el1 + 31) >> 5;
    const int w2_ = (el2 + 31) >> 5, w3_ = (el3 + 31) >> 5;
    const int n0 = 16 * w0_, n1 = n0 + 16 * w1_, n2 = n1 + 16 * w2_;
    const int nvalid = n2 + 16 * w3_;

    const int lane = t & 63, qd = lane >> 4, c = lane & 15;
    const float sc = 0.125f * 1.44269504f;   // 1/sqrt(D) * log2(e)

    for (;;) {
        int mytk = 0;
        if (lane == 0) mytk = atomicAdd(ticket, 1);
        const int it = __shfl(mytk, 0);
        if (it >= nvalid) break;

        int b, u, wb, el;
        if      (it < n0) { b = 0; u = it;      wb = w0_; el = el0; }
        else if (it < n1) { b = 1; u = it - n0; wb = w1_; el = el1; }
        else if (it < n2) { b = 2; u = it - n1; wb = w2_; el = el2; }
        else              { b = 3; u = it - n2; wb = w3_; el = el3; }
        const int head  = u / wb;
        const int qt    = u - head * wb;
        const int bh    = b * 16 + head;
        const int qbase = qt * 32;

        const float* Qp = Q + (size_t)bh * SQ * DH;
        float*       Op = O + (size_t)bh * SQ * DH;
        const size_t tb = (size_t)bh * NTILE * TILE_B + (size_t)lane * 16;
        const char*  Kt = Kbt + tb;
        const char*  Vt = Vbt + tb;

        // Q fragments (B-operand of S^T = K*Q^T); scale folded in
        bf16x8 qf[2][2];
        #pragma unroll
        for (int nt = 0; nt < 2; ++nt) {
            const int row = qbase + nt * 16 + c;
            #pragma unroll
            for (int kc = 0; kc < 2; ++kc) {
                const float* p = Qp + (size_t)row * DH + kc * 32 + qd * 8;
                f32x4 a  = *(const f32x4*)p;
                f32x4 bq = *(const f32x4*)(p + 4);
                u32x4 f;
                f[0] = pk2(a[0] * sc, a[1] * sc);
                f[1] = pk2(a[2] * sc, a[3] * sc);
                f[2] = pk2(bq[0] * sc, bq[1] * sc);
                f[3] = pk2(bq[2] * sc, bq[3] * sc);
                qf[nt][kc] = *(bf16x8*)&f;
            }
        }

        float l_[2] = {0.f, 0.f};
        f32x4 oacc[4][2];
        #pragma unroll
        for (int dt = 0; dt < 4; ++dt) {
            oacc[dt][0] = (f32x4){0.f, 0.f, 0.f, 0.f};
            oacc[dt][1] = (f32x4){0.f, 0.f, 0.f, 0.f};
        }

        const int nkt = (el + TK - 1) >> 6;

        for (int kt = 0; kt < nkt; ++kt) {
            const char* kb = Kt + (size_t)kt * TILE_B;
            const char* vb = Vt + (size_t)kt * TILE_B;

            // fragment loads: 16 coalesced dwordx4 (1KB/wave each), L2/L3-hit
            bf16x8 ka[8];
            #pragma unroll
            for (int i = 0; i < 8; ++i)
                ka[i] = *(const bf16x8*)(kb + i * 1024);
            bf16x8 va[8];
            #pragma unroll
            for (int i = 0; i < 8; ++i)
                va[i] = *(const bf16x8*)(vb + i * 1024);

            const int k0 = kt * TK;
            const bool straddle = (k0 + TK > el);

            // ---- S^T = K*Q^T, mask, exp2, pack -- fused per 16-key subtile ----
            u32x4 pw[2][2];
            #pragma unroll
            for (int mt = 0; mt < 4; ++mt) {
                f32x4 s0 = (f32x4){0.f, 0.f, 0.f, 0.f};
                s0 = __builtin_amdgcn_mfma_f32_16x16x32_bf16(ka[mt*2],   qf[0][0], s0, 0, 0, 0);
                s0 = __builtin_amdgcn_mfma_f32_16x16x32_bf16(ka[mt*2+1], qf[0][1], s0, 0, 0, 0);
                f32x4 s1 = (f32x4){0.f, 0.f, 0.f, 0.f};
                s1 = __builtin_amdgcn_mfma_f32_16x16x32_bf16(ka[mt*2],   qf[1][0], s1, 0, 0, 0);
                s1 = __builtin_amdgcn_mfma_f32_16x16x32_bf16(ka[mt*2+1], qf[1][1], s1, 0, 0, 0);

                if (straddle) {
                    #pragma unroll
                    for (int r = 0; r < 4; ++r)
                        if (k0 + mt * 16 + qd * 4 + r >= el) {
                            s0[r] = -1e30f;
                            s1[r] = -1e30f;
                        }
                }

                #pragma unroll
                for (int nt = 0; nt < 2; ++nt) {
                    const f32x4 s = nt ? s1 : s0;
                    const float p0 = __builtin_amdgcn_exp2f(s[0]);
                    const float p1 = __builtin_amdgcn_exp2f(s[1]);
                    const float p2 = __builtin_amdgcn_exp2f(s[2]);
                    const float p3 = __builtin_amdgcn_exp2f(s[3]);
                    l_[nt] += (p0 + p1) + (p2 + p3);
                    pw[nt][mt >> 1][(mt & 1) * 2]     = pk2(p0, p1);
                    pw[nt][mt >> 1][(mt & 1) * 2 + 1] = pk2(p2, p3);
                }
            }

            // ---- O^T += V^T * P^T : V lines are pi-permuted, P in-register ----
            #pragma unroll
            for (int kc = 0; kc < 2; ++kc) {
                bf16x8 pb0 = *(bf16x8*)&pw[0][kc];
                bf16x8 pb1 = *(bf16x8*)&pw[1][kc];
                #pragma unroll
                for (int dt = 0; dt < 4; ++dt) {
                    bf16x8 vf = va[kc * 4 + dt];
                    oacc[dt][0] = __builtin_amdgcn_mfma_f32_16x16x32_bf16(vf, pb0, oacc[dt][0], 0, 0, 0);
                    oacc[dt][1] = __builtin_amdgcn_mfma_f32_16x16x32_bf16(vf, pb1, oacc[dt][1], 0, 0, 0);
                }
            }
        }

        // denominators: cross-lane combine over qd groups (same query col c)
        #pragma unroll
        for (int nt = 0; nt < 2; ++nt) {
            l_[nt] += __shfl_xor(l_[nt], 16);
            l_[nt] += __shfl_xor(l_[nt], 32);
        }

        #pragma unroll
        for (int nt = 0; nt < 2; ++nt) {
            const int qrow = qbase + nt * 16 + c;
            if (qrow < el) {
                const float inv = 1.0f / l_[nt];
                #pragma unroll
                for (int dt = 0; dt < 4; ++dt) {
                    f32x4 o = oacc[dt][nt];
                    o[0] *= inv; o[1] *= inv; o[2] *= inv; o[3] *= inv;
                    *(f32x4*)(Op + (size_t)qrow * DH + dt * 16 + qd * 4) = o;
                }
            } else {
                #pragma unroll
                for (int dt = 0; dt < 4; ++dt)
                    *(f32x4*)(Op + (size_t)qrow * DH + dt * 16 + qd * 4) =
                        *(const f32x4*)(MV + bh * DH + dt * 16 + qd * 4);
            }
        }
    }
}

// ============================================================================
// FALLBACK PATH (proven R5 kernels, used when ws_size < ~33.6 MB)
// ============================================================================

__global__ __launch_bounds__(256)
void meanv_k(const float* __restrict__ V, float* __restrict__ MV) {
    const int bh  = blockIdx.x >> 4;
    const int seg = blockIdx.x & 15;
    const float* vp = V + ((size_t)bh * SQ + (size_t)seg * 128) * DH;
    const int c = threadIdx.x & 15;
    const int r = threadIdx.x >> 4;
    const float* p = vp + (size_t)r * DH + c * 4;
    f32x4 s0 = *(const f32x4*)(p);
    f32x4 s1 = *(const f32x4*)(p + 16 * DH);
    f32x4 s2 = *(const f32x4*)(p + 32 * DH);
    f32x4 s3 = *(const f32x4*)(p + 48 * DH);
    s0 += *(const f32x4*)(p + 64 * DH);
    s1 += *(const f32x4*)(p + 80 * DH);
    s2 += *(const f32x4*)(p + 96 * DH);
    s3 += *(const f32x4*)(p + 112 * DH);
    f32x4 s = (s0 + s1) + (s2 + s3);
    __shared__ f32x4 red[16][16];
    red[r][c] = s;
    __syncthreads();
    if (threadIdx.x < 16) {
        f32x4 a = red[0][threadIdx.x];
        #pragma unroll
        for (int j = 1; j < 16; ++j) a += red[j][threadIdx.x];
        const float inv = 1.0f / (float)SQ;
        atomicAdd(&MV[bh * DH + threadIdx.x * 4 + 0], a[0] * inv);
        atomicAdd(&MV[bh * DH + threadIdx.x * 4 + 1], a[1] * inv);
        atomicAdd(&MV[bh * DH + threadIdx.x * 4 + 2], a[2] * inv);
        atomicAdd(&MV[bh * DH + threadIdx.x * 4 + 3], a[3] * inv);
    }
}

__global__ __launch_bounds__(256, 3)
void flash5(const float* __restrict__ Q, const float* __restrict__ K,
            const float* __restrict__ V, const int* __restrict__ EL,
            const float* __restrict__ MV, float* __restrict__ O,
            int* __restrict__ ticket) {
    const int t = threadIdx.x;
    {
        const int bh0    = blockIdx.x & (NBH - 1);
        const int qbase0 = (blockIdx.x >> 6) * 128;
        const int elb    = EL[bh0 >> 4];
        if (qbase0 >= elb) {
            float* Op = O + (size_t)bh0 * SQ * DH;
            const int c16 = t & 15, r0 = t >> 4;
            f32x4 mv = *(const f32x4*)(MV + bh0 * DH + c16 * 4);
            #pragma unroll
            for (int i = 0; i < 8; ++i)
                *(f32x4*)(Op + (size_t)(qbase0 + r0 + i * 16) * DH + c16 * 4) = mv;
        }
    }

    const int el0 = EL[0], el1 = EL[1], el2 = EL[2], el3 = EL[3];
    const int v0 = (el0 + 127) >> 7, v1 = (el1 + 127) >> 7;
    const int v2 = (el2 + 127) >> 7, v3 = (el3 + 127) >> 7;
    const int n0 = 16 * v0, n1 = n0 + 16 * v1, n2 = n1 + 16 * v2;
    const int nvalid = n2 + 16 * v3;

    __shared__ short Kb[TK][LDE];
    __shared__ short Vt[DH][LDE];
    __shared__ short Pl[4][32][LDE];
    __shared__ int item_s;

    const int wq = t >> 6, lane = t & 63, qd = lane >> 4, c = lane & 15;
    const int ksrow = t >> 2;
    const int ksdc  = t & 3;
    const int vpair = t & 31;
    const int vdg   = t >> 5;

    for (;;) {
        if (t == 0) item_s = atomicAdd(ticket, 1);
        __syncthreads();
        const int it = item_s;
        if (it >= nvalid) break;

        int b, u, vb, el;
        if      (it < n0) { b = 0; u = it;      vb = v0; el = el0; }
        else if (it < n1) { b = 1; u = it - n0; vb = v1; el = el1; }
        else if (it < n2) { b = 2; u = it - n1; vb = v2; el = el2; }
        else              { b = 3; u = it - n2; vb = v3; el = el3; }
        const int head  = u / vb;
        const int qt    = u - head * vb;
        const int bh    = b * 16 + head;
        const int qbase = qt * 128;

        const size_t base = (size_t)bh * SQ * DH;
        const float* Qp = Q + base;
        const float* Kp = K + base;
        const float* Vp = V + base;
        float* Op = O + base;

        const float sc = 0.125f * 1.44269504f;
        bf16x8 qf[2][2];
        #pragma unroll
        for (int nt = 0; nt < 2; ++nt) {
            const int row = qbase + wq * 32 + nt * 16 + c;
            #pragma unroll
            for (int kc = 0; kc < 2; ++kc) {
                const float* p = Qp + (size_t)row * DH + kc * 32 + qd * 8;
                f32x4 a  = *(const f32x4*)p;
                f32x4 bb = *(const f32x4*)(p + 4);
                u32x4 f;
                f[0] = pk2(a[0] * sc, a[1] * sc);
                f[1] = pk2(a[2] * sc, a[3] * sc);
                f[2] = pk2(bb[0] * sc, bb[1] * sc);
                f[3] = pk2(bb[2] * sc, bb[3] * sc);
                qf[nt][kc] = *(bf16x8*)&f;
            }
        }

        float l_[2] = {0.f, 0.f};
        f32x4 oacc[4][2];
        #pragma unroll
        for (int dt = 0; dt < 4; ++dt)
            #pragma unroll
            for (int nt = 0; nt < 2; ++nt)
                oacc[dt][nt] = (f32x4){0.f, 0.f, 0.f, 0.f};

        const int nkt = (el + TK - 1) / TK;

        f32x4 kg0, kg1, kg2, kg3, vg0, vg1, vg2, vg3;
        {
            const float* kp = Kp + (size_t)ksrow * DH + ksdc * 16;
            kg0 = *(const f32x4*)kp;
            kg1 = *(const f32x4*)(kp + 4);
            kg2 = *(const f32x4*)(kp + 8);
            kg3 = *(const f32x4*)(kp + 12);
            const float* vp0 = Vp + (size_t)(2 * vpair) * DH + vdg * 8;
            vg0 = *(const f32x4*)vp0;
            vg1 = *(const f32x4*)(vp0 + 4);
            vg2 = *(const f32x4*)(vp0 + DH);
            vg3 = *(const f32x4*)(vp0 + DH + 4);
        }

        for (int kt = 0; kt < nkt; ++kt) {
            const int k0 = kt * TK;

            __syncthreads();
            {
                u32x4 w0, w1;
                w0[0] = pk2(kg0[0], kg0[1]); w0[1] = pk2(kg0[2], kg0[3]);
                w0[2] = pk2(kg1[0], kg1[1]); w0[3] = pk2(kg1[2], kg1[3]);
                w1[0] = pk2(kg2[0], kg2[1]); w1[1] = pk2(kg2[2], kg2[3]);
                w1[2] = pk2(kg3[0], kg3[1]); w1[3] = pk2(kg3[2], kg3[3]);
                *(u32x4*)&Kb[ksrow][ksdc * 16]     = w0;
                *(u32x4*)&Kb[ksrow][ksdc * 16 + 8] = w1;
            }
            {
                #pragma unroll
                for (int i = 0; i < 4; ++i) {
                    *(unsigned int*)&Vt[vdg * 8 + i][2 * vpair]     = pk2(vg0[i], vg2[i]);
                    *(unsigned int*)&Vt[vdg * 8 + 4 + i][2 * vpair] = pk2(vg1[i], vg3[i]);
                }
            }
            __syncthreads();

            if (kt + 1 < nkt) {
                const int kn = k0 + TK;
                const float* kp = Kp + (size_t)(kn + ksrow) * DH + ksdc * 16;
                kg0 = *(const f32x4*)kp;
                kg1 = *(const f32x4*)(kp + 4);
                kg2 = *(const f32x4*)(kp + 8);
                kg3 = *(const f32x4*)(kp + 12);
                const float* vp0 = Vp + (size_t)(kn + 2 * vpair) * DH + vdg * 8;
                vg0 = *(const f32x4*)vp0;
                vg1 = *(const f32x4*)(vp0 + 4);
                vg2 = *(const f32x4*)(vp0 + DH);
                vg3 = *(const f32x4*)(vp0 + DH + 4);
            }

            f32x4 st[4][2];
            #pragma unroll
            for (int mt = 0; mt < 4; ++mt) {
                bf16x8 a0 = *(const bf16x8*)&Kb[mt * 16 + c][qd * 8];
                bf16x8 a1 = *(const bf16x8*)&Kb[mt * 16 + c][32 + qd * 8];
                #pragma unroll
                for (int nt = 0; nt < 2; ++nt) {
                    f32x4 acc = (f32x4){0.f, 0.f, 0.f, 0.f};
                    acc = __builtin_amdgcn_mfma_f32_16x16x32_bf16(a0, qf[nt][0], acc, 0, 0, 0);
                    acc = __builtin_amdgcn_mfma_f32_16x16x32_bf16(a1, qf[nt][1], acc, 0, 0, 0);
                    st[mt][nt] = acc;
                }
            }

            if (k0 + TK > el) {
                #pragma unroll
                for (int mt = 0; mt < 4; ++mt)
                    #pragma unroll
                    for (int r = 0; r < 4; ++r)
                        if (k0 + mt * 16 + qd * 4 + r >= el) {
                            st[mt][0][r] = -1e30f;
                            st[mt][1][r] = -1e30f;
                        }
            }

            #pragma unroll
            for (int nt = 0; nt < 2; ++nt) {
                #pragma unroll
                for (int mt = 0; mt < 4; ++mt) {
                    const float p0 = exp2f(st[mt][nt][0]);
                    const float p1 = exp2f(st[mt][nt][1]);
                    const float p2 = exp2f(st[mt][nt][2]);
                    const float p3 = exp2f(st[mt][nt][3]);
                    l_[nt] += (p0 + p1) + (p2 + p3);
                    u32x2 pw;
                    pw[0] = pk2(p0, p1);
                    pw[1] = pk2(p2, p3);
                    *(u32x2*)&Pl[wq][nt * 16 + c][mt * 16 + qd * 4] = pw;
                }
            }

            #pragma unroll
            for (int kc = 0; kc < 2; ++kc) {
                bf16x8 pb0 = *(const bf16x8*)&Pl[wq][c][kc * 32 + qd * 8];
                bf16x8 pb1 = *(const bf16x8*)&Pl[wq][16 + c][kc * 32 + qd * 8];
                #pragma unroll
                for (int dt = 0; dt < 4; ++dt) {
                    bf16x8 vf = *(const bf16x8*)&Vt[dt * 16 + c][kc * 32 + qd * 8];
                    oacc[dt][0] = __builtin_amdgcn_mfma_f32_16x16x32_bf16(vf, pb0, oacc[dt][0], 0, 0, 0);
                    oacc[dt][1] = __builtin_amdgcn_mfma_f32_16x16x32_bf16(vf, pb1, oacc[dt][1], 0, 0, 0);
                }
            }
        }

        #pragma unroll
        for (int nt = 0; nt < 2; ++nt) {
            l_[nt] += __shfl_xor(l_[nt], 16);
            l_[nt] += __shfl_xor(l_[nt], 32);
        }

        #pragma unroll
        for (int nt = 0; nt < 2; ++nt) {
            const int row = qbase + wq * 32 + nt * 16 + c;
            if (row < el) {
                const float inv = 1.0f / l_[nt];
                #pragma unroll
                for (int dt = 0; dt < 4; ++dt) {
                    f32x4 o = oacc[dt][nt];
                    o[0] *= inv; o[1] *= inv; o[2] *= inv; o[3] *= inv;
                    *(f32x4*)(Op + (size_t)row * DH + dt * 16 + qd * 4) = o;
                }
            } else {
                #pragma unroll
                for (int dt = 0; dt < 4; ++dt) {
                    f32x4 mv = *(const f32x4*)(MV + bh * DH + dt * 16 + qd * 4);
                    *(f32x4*)(Op + (size_t)row * DH + dt * 16 + qd * 4) = mv;
                }
            }
        }
    }
}

// ============================================================================

extern "C" void kernel_launch(void* const* d_in, const int* in_sizes, int n_in,
                              void* d_out, int out_size, void* d_ws, size_t ws_size,
                              hipStream_t stream) {
    const float* q  = (const float*)d_in[0];
    const float* k  = (const float*)d_in[1];
    const float* v  = (const float*)d_in[2];
    const int*   el = (const int*)d_in[3];
    float* out = (float*)d_out;

    const size_t kbt_bytes = (size_t)NBH * NTILE * TILE_B;      // 16 MiB
    const size_t needed    = 65536 + 2 * kbt_bytes;             // ~33.6 MiB

    if (ws_size >= needed) {
        // new path: fragment-ordered prepass + wave-independent flash
        float* mv  = (float*)d_ws;
        int*   tk  = (int*)((char*)d_ws + 16384);
        char*  kbt = (char*)d_ws + 65536;
        char*  vbt = kbt + kbt_bytes;

        hipMemsetAsync(d_ws, 0, 65536, stream);
        convkv<<<dim3(NBH * NTILE), dim3(256), 0, stream>>>(k, v, el, mv, kbt, vbt);
        flash8<<<dim3(NBH * (SQ / 128)), dim3(256), 0, stream>>>(q, el, mv, out, kbt, vbt, tk);
    } else {
        // fallback: proven R5 path
        float* mv = (float*)d_ws;
        int*   tk = (int*)((char*)d_ws + NBH * DH * sizeof(float));

        hipMemsetAsync(d_ws, 0, NBH * DH * sizeof(float) + 64, stream);
        meanv_k<<<dim3(NBH * 16), dim3(256), 0, stream>>>(v, mv);
        flash5<<<dim3(NBH * (SQ / 128)), dim3(256), 0, stream>>>(q, k, v, el, mv, out, tk);
    }
}

// Round 4
// 198.267 us; speedup vs baseline: 1.0614x; 1.0614x over previous
//
#include <hip/hip_runtime.h>
#include <hip/hip_bf16.h>

// InnocentAttention: B=4 H=16 S=2048 D=64, fp32 in/out, per-batch event_length mask.
//
// R9: fragment-ordered prepass (validated in R8) + LDS-staged main kernel with a
// 3-deep buffer ring and COUNTED vmcnt (never drains to 0 in the k-loop): per
// tile {barrier; issue T(kt+2); vmcnt(4); barrier; compute} -- loads for two
// future tiles stay in flight across barriers (T3/T4), killing the per-tile
// vmcnt(0)+barrier drain that capped R6/R7. Fragment-ordered lines mean every
// ds_read_b128 is a contiguous 1KB wave read (conflict-free, no swizzle) and
// feeds MFMA operands directly. 8 waves x 16 q = 128-q items; 48KB LDS -> 3
// blocks/CU = 24 waves/CU. setprio(1) around MFMA clusters (T5).
// Falls back to the proven R5 path when ws_size < ~33.6 MB.

#define SQ 2048
#define DH 64
#define NBH 64
#define TK 64
#define NTILE 32           // SQ / TK
#define TILE_B 8192        // TK * DH * 2 bytes (bf16)
#define LDE 72             // fallback-path padded LDS stride
#define LVP 68             // prepass V-stage stride

typedef __attribute__((ext_vector_type(4))) float f32x4;
typedef __attribute__((ext_vector_type(8))) short bf16x8;
typedef __attribute__((ext_vector_type(4))) unsigned int u32x4;
typedef __attribute__((ext_vector_type(2))) unsigned int u32x2;

#define VMCNT(n) asm volatile("s_waitcnt vmcnt(" #n ")" ::: "memory")

__device__ __forceinline__ unsigned int pk2(float lo, float hi) {
    // v_cvt_pk_bf16_f32 on gfx950 (RNE), lo -> low 16 bits
    __hip_bfloat162 h = __float22bfloat162_rn(float2{lo, hi});
    union { __hip_bfloat162 h; unsigned int u; } c; c.h = h;
    return c.u;
}

__device__ __forceinline__ float bfu16_to_f(unsigned short s) {
    union { unsigned int u; float f; } c; c.u = ((unsigned int)s) << 16;
    return c.f;
}

__device__ __forceinline__ void async_cp16(const void* g, void* l) {
    // global -> LDS direct DMA, 16B/lane; LDS dest = wave-uniform base + lane*16
    __builtin_amdgcn_global_load_lds(
        (const __attribute__((address_space(1))) unsigned int*)g,
        (__attribute__((address_space(3))) unsigned int*)l, 16, 0, 0);
}

// ============================================================================
// NEW PATH
// ============================================================================

// Prepass (validated in R8): one block per (bh, 64-key tile). Fragment-ordered:
//  K tile: line fi = mt*2+half (1KB); lane l=(qd*16+c): 16B =
//          K[key=mt*16+c][d = half*32+qd*8 .. +7] bf16.
//  V tile: line fi = kc*4+dt; lane l: element j =
//          V[key = kc*32 + (j>>2)*16 + qd*4 + (j&3)][d = dt*16+c]  (pi order)
//  MV[bh][d] += mean contribution of this tile's 64 V rows (atomic)
__global__ __launch_bounds__(256)
void convkv(const float* __restrict__ K, const float* __restrict__ V,
            const int* __restrict__ EL, float* __restrict__ MV,
            char* __restrict__ Kbt, char* __restrict__ Vbt) {
    const int bh = blockIdx.x >> 5;
    const int kt = blockIdx.x & 31;
    const int k0 = kt * TK;
    const int el = EL[bh >> 4];
    const int t = threadIdx.x;
    const int r  = t >> 2;      // key row 0..63
    const int dc = t & 3;       // 16-d chunk

    __shared__ short LV[64][LVP];

    // stage V row (bf16) into LDS for transpose + mean
    {
        const float* vp = V + ((size_t)bh * SQ + k0 + r) * DH + dc * 16;
        f32x4 a = *(const f32x4*)vp;
        f32x4 b = *(const f32x4*)(vp + 4);
        f32x4 c2 = *(const f32x4*)(vp + 8);
        f32x4 d2 = *(const f32x4*)(vp + 12);
        u32x4 w0, w1;
        w0[0] = pk2(a[0], a[1]);  w0[1] = pk2(a[2], a[3]);
        w0[2] = pk2(b[0], b[1]);  w0[3] = pk2(b[2], b[3]);
        w1[0] = pk2(c2[0], c2[1]); w1[1] = pk2(c2[2], c2[3]);
        w1[2] = pk2(d2[0], d2[1]); w1[3] = pk2(d2[2], d2[3]);
        *(u32x4*)&LV[r][dc * 16]     = w0;
        *(u32x4*)&LV[r][dc * 16 + 8] = w1;
    }

    // K convert (valid tiles only) -> fragment-ordered lines
    if (k0 < el) {
        const float* kp = K + ((size_t)bh * SQ + k0 + r) * DH + dc * 16;
        f32x4 a = *(const f32x4*)kp;
        f32x4 b = *(const f32x4*)(kp + 4);
        f32x4 c2 = *(const f32x4*)(kp + 8);
        f32x4 d2 = *(const f32x4*)(kp + 12);
        u32x4 w0, w1;
        w0[0] = pk2(a[0], a[1]);  w0[1] = pk2(a[2], a[3]);
        w0[2] = pk2(b[0], b[1]);  w0[3] = pk2(b[2], b[3]);
        w1[0] = pk2(c2[0], c2[1]); w1[1] = pk2(c2[2], c2[3]);
        w1[2] = pk2(d2[0], d2[1]); w1[3] = pk2(d2[2], d2[3]);
        char* kb = Kbt + (size_t)(bh * NTILE + kt) * TILE_B;
        const int fi  = (r >> 4) * 2 + (dc >> 1);
        const int qd0 = (dc & 1) * 2;
        char* d0 = kb + fi * 1024 + qd0 * 256 + (r & 15) * 16;
        *(u32x4*)d0         = w0;
        *(u32x4*)(d0 + 256) = w1;
    }

    __syncthreads();

    // transpose-read V in pi order + mean partial
    const int dd  = t >> 2;     // d row 0..63
    const int seg = t & 3;      // 16-pos segment
    float msum = 0.f;
    unsigned int wv[8];
    #pragma unroll
    for (int i = 0; i < 8; ++i) {
        const int pos = seg * 16 + 2 * i;
        const int key = (pos & ~31) | ((pos & 4) << 2) | ((pos & 24) >> 1) | (pos & 3);
        const unsigned short s0 = (unsigned short)LV[key][dd];
        const unsigned short s1 = (unsigned short)LV[key + 1][dd];
        msum += bfu16_to_f(s0) + bfu16_to_f(s1);
        wv[i] = (unsigned int)s0 | ((unsigned int)s1 << 16);
    }
    msum += __shfl_xor(msum, 1);
    msum += __shfl_xor(msum, 2);
    if (seg == 0) atomicAdd(&MV[bh * DH + dd], msum * (1.0f / (float)SQ));

    if (k0 < el) {
        char* vbb = Vbt + (size_t)(bh * NTILE + kt) * TILE_B;
        const int fi  = (seg >> 1) * 4 + (dd >> 4);
        const int qd0 = (seg & 1) * 2;
        char* d0 = vbb + fi * 1024 + qd0 * 256 + (dd & 15) * 16;
        u32x4 o0 = {wv[0], wv[1], wv[2], wv[3]};
        u32x4 o1 = {wv[4], wv[5], wv[6], wv[7]};
        *(u32x4*)d0         = o0;
        *(u32x4*)(d0 + 256) = o1;
    }
}

// Main kernel: 512 threads = 8 waves x 16 queries = 128-q items.
// 3-deep LDS ring, counted vmcnt, fragment-line ds_read_b128.
__global__ __launch_bounds__(512, 6)
void flash9(const float* __restrict__ Q, const int* __restrict__ EL,
            const float* __restrict__ MV, float* __restrict__ O,
            const char* __restrict__ Kbt, const char* __restrict__ Vbt,
            int* __restrict__ ticket) {
    const int t = threadIdx.x;

    // ---------- static phase: mean(V) rows for own masked q-block ----------
    {
        const int bh0 = blockIdx.x & (NBH - 1);
        const int qb0 = (blockIdx.x >> 6) * 128;
        const int elb = EL[bh0 >> 4];
        if (qb0 >= elb) {
            float* Op = O + (size_t)bh0 * SQ * DH;
            const int c16 = t & 15, r0 = t >> 4;    // r0 0..31
            f32x4 mv = *(const f32x4*)(MV + bh0 * DH + c16 * 4);
            #pragma unroll
            for (int i = 0; i < 4; ++i)
                *(f32x4*)(Op + (size_t)(qb0 + r0 + i * 32) * DH + c16 * 4) = mv;
        }
    }

    // ---------- dynamic phase ----------
    const int el0 = EL[0], el1 = EL[1], el2 = EL[2], el3 = EL[3];
    const int v0 = (el0 + 127) >> 7, v1 = (el1 + 127) >> 7;
    const int v2 = (el2 + 127) >> 7, v3 = (el3 + 127) >> 7;
    const int n0 = 16 * v0, n1 = n0 + 16 * v1, n2 = n1 + 16 * v2;
    const int nvalid = n2 + 16 * v3;

    __shared__ char KB[3 * TILE_B];
    __shared__ char VB[3 * TILE_B];
    __shared__ int item_s;

    const int wq = t >> 6, lane = t & 63, qd = lane >> 4, c = lane & 15;
    const float sc = 0.125f * 1.44269504f;   // 1/sqrt(D) * log2(e)

    for (;;) {
        if (t == 0) item_s = atomicAdd(ticket, 1);
        __syncthreads();                 // broadcast + all waves done with LDS
        const int it = item_s;
        if (it >= nvalid) break;

        int b, u, vb, el;
        if      (it < n0) { b = 0; u = it;      vb = v0; el = el0; }
        else if (it < n1) { b = 1; u = it - n0; vb = v1; el = el1; }
        else if (it < n2) { b = 2; u = it - n1; vb = v2; el = el2; }
        else              { b = 3; u = it - n2; vb = v3; el = el3; }
        const int head  = u / vb;
        const int qt    = u - head * vb;
        const int bh    = b * 16 + head;
        const int qbase = qt * 128;

        const float* Qp = Q + (size_t)bh * SQ * DH;
        float*       Op = O + (size_t)bh * SQ * DH;
        const char*  Kt = Kbt + (size_t)bh * NTILE * TILE_B + t * 16;
        const char*  Vt = Vbt + (size_t)bh * NTILE * TILE_B + t * 16;
        char* const  kdst = KB + wq * 1024;
        char* const  vdst = VB + wq * 1024;

        const int nkt = (el + TK - 1) >> 6;

        // prologue: tiles 0 and 1 in flight (2 VMEM instr per wave per tile)
        async_cp16(Kt, kdst);
        async_cp16(Vt, vdst);
        if (nkt > 1) {
            async_cp16(Kt + TILE_B, kdst + TILE_B);
            async_cp16(Vt + TILE_B, vdst + TILE_B);
        }

        // Q fragments (B-operand of S^T = K*Q^T); scale folded in
        const int qrow = qbase + wq * 16 + c;
        bf16x8 qf[2];
        #pragma unroll
        for (int kc = 0; kc < 2; ++kc) {
            const float* p = Qp + (size_t)qrow * DH + kc * 32 + qd * 8;
            f32x4 a  = *(const f32x4*)p;
            f32x4 bq = *(const f32x4*)(p + 4);
            u32x4 f;
            f[0] = pk2(a[0] * sc, a[1] * sc);
            f[1] = pk2(a[2] * sc, a[3] * sc);
            f[2] = pk2(bq[0] * sc, bq[1] * sc);
            f[3] = pk2(bq[2] * sc, bq[3] * sc);
            qf[kc] = *(bf16x8*)&f;
        }

        float l_ = 0.f;
        f32x4 oacc[4];
        #pragma unroll
        for (int dt = 0; dt < 4; ++dt) oacc[dt] = (f32x4){0.f, 0.f, 0.f, 0.f};

        for (int kt = 0; kt < nkt; ++kt) {
            const int s = kt % 3;

            // all waves finished computing tile kt-1 -> its future slot is free
            __syncthreads();
            if (kt + 2 < nkt) {
                const int s2 = (kt + 2) % 3;
                async_cp16(Kt + (size_t)(kt + 2) * TILE_B, kdst + s2 * TILE_B);
                async_cp16(Vt + (size_t)(kt + 2) * TILE_B, vdst + s2 * TILE_B);
            }
            // counted wait: own copies of tile kt done; 2 future tiles stay in flight
            if      (kt + 2 < nkt) VMCNT(4);
            else if (kt + 1 < nkt) VMCNT(2);
            else                   VMCNT(0);
            __syncthreads();                 // everyone's tile-kt lines visible

            const char* Kb = KB + s * TILE_B + lane * 16;
            const char* Vb = VB + s * TILE_B + lane * 16;

            // ---- S^T = K * Q^T : contiguous fragment-line reads ----
            bf16x8 ka[8];
            #pragma unroll
            for (int i = 0; i < 8; ++i)
                ka[i] = *(const bf16x8*)(Kb + i * 1024);

            f32x4 st[4];
            __builtin_amdgcn_s_setprio(1);
            #pragma unroll
            for (int mt = 0; mt < 4; ++mt) {
                f32x4 acc = (f32x4){0.f, 0.f, 0.f, 0.f};
                acc = __builtin_amdgcn_mfma_f32_16x16x32_bf16(ka[mt*2],   qf[0], acc, 0, 0, 0);
                acc = __builtin_amdgcn_mfma_f32_16x16x32_bf16(ka[mt*2+1], qf[1], acc, 0, 0, 0);
                st[mt] = acc;
            }
            __builtin_amdgcn_s_setprio(0);

            const int k0 = kt * TK;
            if (k0 + TK > el) {    // straddling tile: mask invalid keys
                #pragma unroll
                for (int mt = 0; mt < 4; ++mt)
                    #pragma unroll
                    for (int r = 0; r < 4; ++r)
                        if (k0 + mt * 16 + qd * 4 + r >= el) st[mt][r] = -1e30f;
            }

            // ---- p = exp2(s); pack in-register (pi order == lane's own keys) ----
            u32x4 pw[2];
            #pragma unroll
            for (int mt = 0; mt < 4; ++mt) {
                const float p0 = __builtin_amdgcn_exp2f(st[mt][0]);
                const float p1 = __builtin_amdgcn_exp2f(st[mt][1]);
                const float p2 = __builtin_amdgcn_exp2f(st[mt][2]);
                const float p3 = __builtin_amdgcn_exp2f(st[mt][3]);
                l_ += (p0 + p1) + (p2 + p3);
                pw[mt >> 1][(mt & 1) * 2]     = pk2(p0, p1);
                pw[mt >> 1][(mt & 1) * 2 + 1] = pk2(p2, p3);
            }

            // ---- O^T += V^T * P^T : V lines pi-permuted, P in-register ----
            bf16x8 va[8];
            #pragma unroll
            for (int i = 0; i < 8; ++i)
                va[i] = *(const bf16x8*)(Vb + i * 1024);

            __builtin_amdgcn_s_setprio(1);
            #pragma unroll
            for (int kc = 0; kc < 2; ++kc) {
                bf16x8 pb = *(bf16x8*)&pw[kc];
                #pragma unroll
                for (int dt = 0; dt < 4; ++dt)
                    oacc[dt] = __builtin_amdgcn_mfma_f32_16x16x32_bf16(va[kc*4+dt], pb, oacc[dt], 0, 0, 0);
            }
            __builtin_amdgcn_s_setprio(0);
        }

        // denominator: cross-lane combine over qd groups (same query col c)
        l_ += __shfl_xor(l_, 16);
        l_ += __shfl_xor(l_, 32);

        if (qrow < el) {
            const float inv = 1.0f / l_;
            #pragma unroll
            for (int dt = 0; dt < 4; ++dt) {
                f32x4 o = oacc[dt];
                o[0] *= inv; o[1] *= inv; o[2] *= inv; o[3] *= inv;
                *(f32x4*)(Op + (size_t)qrow * DH + dt * 16 + qd * 4) = o;
            }
        } else {
            #pragma unroll
            for (int dt = 0; dt < 4; ++dt)
                *(f32x4*)(Op + (size_t)qrow * DH + dt * 16 + qd * 4) =
                    *(const f32x4*)(MV + bh * DH + dt * 16 + qd * 4);
        }
    }
}

// ============================================================================
// FALLBACK PATH (proven R5 kernels, used when ws_size < ~33.6 MB)
// ============================================================================

__global__ __launch_bounds__(256)
void meanv_k(const float* __restrict__ V, float* __restrict__ MV) {
    const int bh  = blockIdx.x >> 4;
    const int seg = blockIdx.x & 15;
    const float* vp = V + ((size_t)bh * SQ + (size_t)seg * 128) * DH;
    const int c = threadIdx.x & 15;
    const int r = threadIdx.x >> 4;
    const float* p = vp + (size_t)r * DH + c * 4;
    f32x4 s0 = *(const f32x4*)(p);
    f32x4 s1 = *(const f32x4*)(p + 16 * DH);
    f32x4 s2 = *(const f32x4*)(p + 32 * DH);
    f32x4 s3 = *(const f32x4*)(p + 48 * DH);
    s0 += *(const f32x4*)(p + 64 * DH);
    s1 += *(const f32x4*)(p + 80 * DH);
    s2 += *(const f32x4*)(p + 96 * DH);
    s3 += *(const f32x4*)(p + 112 * DH);
    f32x4 s = (s0 + s1) + (s2 + s3);
    __shared__ f32x4 red[16][16];
    red[r][c] = s;
    __syncthreads();
    if (threadIdx.x < 16) {
        f32x4 a = red[0][threadIdx.x];
        #pragma unroll
        for (int j = 1; j < 16; ++j) a += red[j][threadIdx.x];
        const float inv = 1.0f / (float)SQ;
        atomicAdd(&MV[bh * DH + threadIdx.x * 4 + 0], a[0] * inv);
        atomicAdd(&MV[bh * DH + threadIdx.x * 4 + 1], a[1] * inv);
        atomicAdd(&MV[bh * DH + threadIdx.x * 4 + 2], a[2] * inv);
        atomicAdd(&MV[bh * DH + threadIdx.x * 4 + 3], a[3] * inv);
    }
}

__global__ __launch_bounds__(256, 3)
void flash5(const float* __restrict__ Q, const float* __restrict__ K,
            const float* __restrict__ V, const int* __restrict__ EL,
            const float* __restrict__ MV, float* __restrict__ O,
            int* __restrict__ ticket) {
    const int t = threadIdx.x;
    {
        const int bh0    = blockIdx.x & (NBH - 1);
        const int qbase0 = (blockIdx.x >> 6) * 128;
        const int elb    = EL[bh0 >> 4];
        if (qbase0 >= elb) {
            float* Op = O + (size_t)bh0 * SQ * DH;
            const int c16 = t & 15, r0 = t >> 4;
            f32x4 mv = *(const f32x4*)(MV + bh0 * DH + c16 * 4);
            #pragma unroll
            for (int i = 0; i < 8; ++i)
                *(f32x4*)(Op + (size_t)(qbase0 + r0 + i * 16) * DH + c16 * 4) = mv;
        }
    }

    const int el0 = EL[0], el1 = EL[1], el2 = EL[2], el3 = EL[3];
    const int v0 = (el0 + 127) >> 7, v1 = (el1 + 127) >> 7;
    const int v2 = (el2 + 127) >> 7, v3 = (el3 + 127) >> 7;
    const int n0 = 16 * v0, n1 = n0 + 16 * v1, n2 = n1 + 16 * v2;
    const int nvalid = n2 + 16 * v3;

    __shared__ short Kb[TK][LDE];
    __shared__ short Vt[DH][LDE];
    __shared__ short Pl[4][32][LDE];
    __shared__ int item_s;

    const int wq = t >> 6, lane = t & 63, qd = lane >> 4, c = lane & 15;
    const int ksrow = t >> 2;
    const int ksdc  = t & 3;
    const int vpair = t & 31;
    const int vdg   = t >> 5;

    for (;;) {
        if (t == 0) item_s = atomicAdd(ticket, 1);
        __syncthreads();
        const int it = item_s;
        if (it >= nvalid) break;

        int b, u, vb, el;
        if      (it < n0) { b = 0; u = it;      vb = v0; el = el0; }
        else if (it < n1) { b = 1; u = it - n0; vb = v1; el = el1; }
        else if (it < n2) { b = 2; u = it - n1; vb = v2; el = el2; }
        else              { b = 3; u = it - n2; vb = v3; el = el3; }
        const int head  = u / vb;
        const int qt    = u - head * vb;
        const int bh    = b * 16 + head;
        const int qbase = qt * 128;

        const size_t base = (size_t)bh * SQ * DH;
        const float* Qp = Q + base;
        const float* Kp = K + base;
        const float* Vp = V + base;
        float* Op = O + base;

        const float sc = 0.125f * 1.44269504f;
        bf16x8 qf[2][2];
        #pragma unroll
        for (int nt = 0; nt < 2; ++nt) {
            const int row = qbase + wq * 32 + nt * 16 + c;
            #pragma unroll
            for (int kc = 0; kc < 2; ++kc) {
                const float* p = Qp + (size_t)row * DH + kc * 32 + qd * 8;
                f32x4 a  = *(const f32x4*)p;
                f32x4 bb = *(const f32x4*)(p + 4);
                u32x4 f;
                f[0] = pk2(a[0] * sc, a[1] * sc);
                f[1] = pk2(a[2] * sc, a[3] * sc);
                f[2] = pk2(bb[0] * sc, bb[1] * sc);
                f[3] = pk2(bb[2] * sc, bb[3] * sc);
                qf[nt][kc] = *(bf16x8*)&f;
            }
        }

        float l_[2] = {0.f, 0.f};
        f32x4 oacc[4][2];
        #pragma unroll
        for (int dt = 0; dt < 4; ++dt)
            #pragma unroll
            for (int nt = 0; nt < 2; ++nt)
                oacc[dt][nt] = (f32x4){0.f, 0.f, 0.f, 0.f};

        const int nkt = (el + TK - 1) / TK;

        f32x4 kg0, kg1, kg2, kg3, vg0, vg1, vg2, vg3;
        {
            const float* kp = Kp + (size_t)ksrow * DH + ksdc * 16;
            kg0 = *(const f32x4*)kp;
            kg1 = *(const f32x4*)(kp + 4);
            kg2 = *(const f32x4*)(kp + 8);
            kg3 = *(const f32x4*)(kp + 12);
            const float* vp0 = Vp + (size_t)(2 * vpair) * DH + vdg * 8;
            vg0 = *(const f32x4*)vp0;
            vg1 = *(const f32x4*)(vp0 + 4);
            vg2 = *(const f32x4*)(vp0 + DH);
            vg3 = *(const f32x4*)(vp0 + DH + 4);
        }

        for (int kt = 0; kt < nkt; ++kt) {
            const int k0 = kt * TK;

            __syncthreads();
            {
                u32x4 w0, w1;
                w0[0] = pk2(kg0[0], kg0[1]); w0[1] = pk2(kg0[2], kg0[3]);
                w0[2] = pk2(kg1[0], kg1[1]); w0[3] = pk2(kg1[2], kg1[3]);
                w1[0] = pk2(kg2[0], kg2[1]); w1[1] = pk2(kg2[2], kg2[3]);
                w1[2] = pk2(kg3[0], kg3[1]); w1[3] = pk2(kg3[2], kg3[3]);
                *(u32x4*)&Kb[ksrow][ksdc * 16]     = w0;
                *(u32x4*)&Kb[ksrow][ksdc * 16 + 8] = w1;
            }
            {
                #pragma unroll
                for (int i = 0; i < 4; ++i) {
                    *(unsigned int*)&Vt[vdg * 8 + i][2 * vpair]     = pk2(vg0[i], vg2[i]);
                    *(unsigned int*)&Vt[vdg * 8 + 4 + i][2 * vpair] = pk2(vg1[i], vg3[i]);
                }
            }
            __syncthreads();

            if (kt + 1 < nkt) {
                const int kn = k0 + TK;
                const float* kp = Kp + (size_t)(kn + ksrow) * DH + ksdc * 16;
                kg0 = *(const f32x4*)kp;
                kg1 = *(const f32x4*)(kp + 4);
                kg2 = *(const f32x4*)(kp + 8);
                kg3 = *(const f32x4*)(kp + 12);
                const float* vp0 = Vp + (size_t)(kn + 2 * vpair) * DH + vdg * 8;
                vg0 = *(const f32x4*)vp0;
                vg1 = *(const f32x4*)(vp0 + 4);
                vg2 = *(const f32x4*)(vp0 + DH);
                vg3 = *(const f32x4*)(vp0 + DH + 4);
            }

            f32x4 st[4][2];
            #pragma unroll
            for (int mt = 0; mt < 4; ++mt) {
                bf16x8 a0 = *(const bf16x8*)&Kb[mt * 16 + c][qd * 8];
                bf16x8 a1 = *(const bf16x8*)&Kb[mt * 16 + c][32 + qd * 8];
                #pragma unroll
                for (int nt = 0; nt < 2; ++nt) {
                    f32x4 acc = (f32x4){0.f, 0.f, 0.f, 0.f};
                    acc = __builtin_amdgcn_mfma_f32_16x16x32_bf16(a0, qf[nt][0], acc, 0, 0, 0);
                    acc = __builtin_amdgcn_mfma_f32_16x16x32_bf16(a1, qf[nt][1], acc, 0, 0, 0);
                    st[mt][nt] = acc;
                }
            }

            if (k0 + TK > el) {
                #pragma unroll
                for (int mt = 0; mt < 4; ++mt)
                    #pragma unroll
                    for (int r = 0; r < 4; ++r)
                        if (k0 + mt * 16 + qd * 4 + r >= el) {
                            st[mt][0][r] = -1e30f;
                            st[mt][1][r] = -1e30f;
                        }
            }

            #pragma unroll
            for (int nt = 0; nt < 2; ++nt) {
                #pragma unroll
                for (int mt = 0; mt < 4; ++mt) {
                    const float p0 = exp2f(st[mt][nt][0]);
                    const float p1 = exp2f(st[mt][nt][1]);
                    const float p2 = exp2f(st[mt][nt][2]);
                    const float p3 = exp2f(st[mt][nt][3]);
                    l_[nt] += (p0 + p1) + (p2 + p3);
                    u32x2 pw;
                    pw[0] = pk2(p0, p1);
                    pw[1] = pk2(p2, p3);
                    *(u32x2*)&Pl[wq][nt * 16 + c][mt * 16 + qd * 4] = pw;
                }
            }

            #pragma unroll
            for (int kc = 0; kc < 2; ++kc) {
                bf16x8 pb0 = *(const bf16x8*)&Pl[wq][c][kc * 32 + qd * 8];
                bf16x8 pb1 = *(const bf16x8*)&Pl[wq][16 + c][kc * 32 + qd * 8];
                #pragma unroll
                for (int dt = 0; dt < 4; ++dt) {
                    bf16x8 vf = *(const bf16x8*)&Vt[dt * 16 + c][kc * 32 + qd * 8];
                    oacc[dt][0] = __builtin_amdgcn_mfma_f32_16x16x32_bf16(vf, pb0, oacc[dt][0], 0, 0, 0);
                    oacc[dt][1] = __builtin_amdgcn_mfma_f32_16x16x32_bf16(vf, pb1, oacc[dt][1], 0, 0, 0);
                }
            }
        }

        #pragma unroll
        for (int nt = 0; nt < 2; ++nt) {
            l_[nt] += __shfl_xor(l_[nt], 16);
            l_[nt] += __shfl_xor(l_[nt], 32);
        }

        #pragma unroll
        for (int nt = 0; nt < 2; ++nt) {
            const int row = qbase + wq * 32 + nt * 16 + c;
            if (row < el) {
                const float inv = 1.0f / l_[nt];
                #pragma unroll
                for (int dt = 0; dt < 4; ++dt) {
                    f32x4 o = oacc[dt][nt];
                    o[0] *= inv; o[1] *= inv; o[2] *= inv; o[3] *= inv;
                    *(f32x4*)(Op + (size_t)row * DH + dt * 16 + qd * 4) = o;
                }
            } else {
                #pragma unroll
                for (int dt = 0; dt < 4; ++dt) {
                    f32x4 mv = *(const f32x4*)(MV + bh * DH + dt * 16 + qd * 4);
                    *(f32x4*)(Op + (size_t)row * DH + dt * 16 + qd * 4) = mv;
                }
            }
        }
    }
}

// ============================================================================

extern "C" void kernel_launch(void* const* d_in, const int* in_sizes, int n_in,
                              void* d_out, int out_size, void* d_ws, size_t ws_size,
                              hipStream_t stream) {
    const float* q  = (const float*)d_in[0];
    const float* k  = (const float*)d_in[1];
    const float* v  = (const float*)d_in[2];
    const int*   el = (const int*)d_in[3];
    float* out = (float*)d_out;

    const size_t kbt_bytes = (size_t)NBH * NTILE * TILE_B;      // 16 MiB
    const size_t needed    = 65536 + 2 * kbt_bytes;             // ~33.6 MiB

    if (ws_size >= needed) {
        // new path: fragment-ordered prepass + counted-vmcnt pipelined flash
        float* mv  = (float*)d_ws;
        int*   tk  = (int*)((char*)d_ws + 16384);
        char*  kbt = (char*)d_ws + 65536;
        char*  vbt = kbt + kbt_bytes;

        hipMemsetAsync(d_ws, 0, 65536, stream);
        convkv<<<dim3(NBH * NTILE), dim3(256), 0, stream>>>(k, v, el, mv, kbt, vbt);
        flash9<<<dim3(NBH * (SQ / 128)), dim3(512), 0, stream>>>(q, el, mv, out, kbt, vbt, tk);
    } else {
        // fallback: proven R5 path
        float* mv = (float*)d_ws;
        int*   tk = (int*)((char*)d_ws + NBH * DH * sizeof(float));

        hipMemsetAsync(d_ws, 0, NBH * DH * sizeof(float) + 64, stream);
        meanv_k<<<dim3(NBH * 16), dim3(256), 0, stream>>>(v, mv);
        flash5<<<dim3(NBH * (SQ / 128)), dim3(256), 0, stream>>>(q, k, v, el, mv, out, tk);
    }
}

// Round 6
// 193.806 us; speedup vs baseline: 1.0858x; 1.0230x over previous
//
#include <hip/hip_runtime.h>
#include <hip/hip_bf16.h>

// InnocentAttention: B=4 H=16 S=2048 D=64, fp32 in/out, per-batch event_length mask.
//
// R11 (= R10 with the CSWAP macro identifier bug fixed): R6-R9 plateaued at
// ~78us with all pipes <25% busy -> data-path bound, not schedule bound: the
// global ticket queue scatters same-bh items across XCDs, so K/V workspace
// re-reads are cross-die L3 round trips (R8 calibrated ~7 TB/s / ~600-900cy).
// Fix = XCD-AFFINITY QUEUES: 8 per-head-group ticket queues; block g pulls from
// queue g%8 (blockIdx->XCD round-robin, T1/m157). Per-group working set =
// 8 bh x 0.5MB = 4MB = one XCD's L2 -> re-reads are L2-hits. Also: 256-q items
// (8 waves x 32q, R7-validated math) halve re-read traffic; grid 512 = 2
// blocks/CU all-resident; largest-batch-first item order (register sorting
// network) shrinks the tail. Prepass + 3-ring counted-vmcnt pipeline unchanged
// from R9. Falls back to R5 path when ws_size < ~33.6 MB.

#define SQ 2048
#define DH 64
#define NBH 64
#define TK 64
#define NTILE 32           // SQ / TK
#define TILE_B 8192        // TK * DH * 2 bytes (bf16)
#define LDE 72             // fallback-path padded LDS stride
#define LVP 68             // prepass V-stage stride

typedef __attribute__((ext_vector_type(4))) float f32x4;
typedef __attribute__((ext_vector_type(8))) short bf16x8;
typedef __attribute__((ext_vector_type(4))) unsigned int u32x4;
typedef __attribute__((ext_vector_type(2))) unsigned int u32x2;

#define VMCNT(n) asm volatile("s_waitcnt vmcnt(" #n ")" ::: "memory")

__device__ __forceinline__ unsigned int pk2(float lo, float hi) {
    // v_cvt_pk_bf16_f32 on gfx950 (RNE), lo -> low 16 bits
    __hip_bfloat162 h = __float22bfloat162_rn(float2{lo, hi});
    union { __hip_bfloat162 h; unsigned int u; } c; c.h = h;
    return c.u;
}

__device__ __forceinline__ float bfu16_to_f(unsigned short s) {
    union { unsigned int u; float f; } c; c.u = ((unsigned int)s) << 16;
    return c.f;
}

__device__ __forceinline__ void async_cp16(const void* g, void* l) {
    // global -> LDS direct DMA, 16B/lane; LDS dest = wave-uniform base + lane*16
    __builtin_amdgcn_global_load_lds(
        (const __attribute__((address_space(1))) unsigned int*)g,
        (__attribute__((address_space(3))) unsigned int*)l, 16, 0, 0);
}

// ============================================================================
// NEW PATH
// ============================================================================

// Prepass (validated in R8/R9): one block per (bh, 64-key tile). Fragment-ordered:
//  K tile: line fi = mt*2+half (1KB); lane l=(qd*16+c): 16B =
//          K[key=mt*16+c][d = half*32+qd*8 .. +7] bf16.
//  V tile: line fi = kc*4+dt; lane l: element j =
//          V[key = kc*32 + (j>>2)*16 + qd*4 + (j&3)][d = dt*16+c]  (pi order)
//  MV[bh][d] += mean contribution of this tile's 64 V rows (atomic)
__global__ __launch_bounds__(256)
void convkv(const float* __restrict__ K, const float* __restrict__ V,
            const int* __restrict__ EL, float* __restrict__ MV,
            char* __restrict__ Kbt, char* __restrict__ Vbt) {
    const int bh = blockIdx.x >> 5;
    const int kt = blockIdx.x & 31;
    const int k0 = kt * TK;
    const int el = EL[bh >> 4];
    const int t = threadIdx.x;
    const int r  = t >> 2;      // key row 0..63
    const int dc = t & 3;       // 16-d chunk

    __shared__ short LV[64][LVP];

    // stage V row (bf16) into LDS for transpose + mean
    {
        const float* vp = V + ((size_t)bh * SQ + k0 + r) * DH + dc * 16;
        f32x4 a = *(const f32x4*)vp;
        f32x4 b = *(const f32x4*)(vp + 4);
        f32x4 c2 = *(const f32x4*)(vp + 8);
        f32x4 d2 = *(const f32x4*)(vp + 12);
        u32x4 w0, w1;
        w0[0] = pk2(a[0], a[1]);  w0[1] = pk2(a[2], a[3]);
        w0[2] = pk2(b[0], b[1]);  w0[3] = pk2(b[2], b[3]);
        w1[0] = pk2(c2[0], c2[1]); w1[1] = pk2(c2[2], c2[3]);
        w1[2] = pk2(d2[0], d2[1]); w1[3] = pk2(d2[2], d2[3]);
        *(u32x4*)&LV[r][dc * 16]     = w0;
        *(u32x4*)&LV[r][dc * 16 + 8] = w1;
    }

    // K convert (valid tiles only) -> fragment-ordered lines
    if (k0 < el) {
        const float* kp = K + ((size_t)bh * SQ + k0 + r) * DH + dc * 16;
        f32x4 a = *(const f32x4*)kp;
        f32x4 b = *(const f32x4*)(kp + 4);
        f32x4 c2 = *(const f32x4*)(kp + 8);
        f32x4 d2 = *(const f32x4*)(kp + 12);
        u32x4 w0, w1;
        w0[0] = pk2(a[0], a[1]);  w0[1] = pk2(a[2], a[3]);
        w0[2] = pk2(b[0], b[1]);  w0[3] = pk2(b[2], b[3]);
        w1[0] = pk2(c2[0], c2[1]); w1[1] = pk2(c2[2], c2[3]);
        w1[2] = pk2(d2[0], d2[1]); w1[3] = pk2(d2[2], d2[3]);
        char* kb = Kbt + (size_t)(bh * NTILE + kt) * TILE_B;
        const int fi  = (r >> 4) * 2 + (dc >> 1);
        const int qd0 = (dc & 1) * 2;
        char* d0 = kb + fi * 1024 + qd0 * 256 + (r & 15) * 16;
        *(u32x4*)d0         = w0;
        *(u32x4*)(d0 + 256) = w1;
    }

    __syncthreads();

    // transpose-read V in pi order + mean partial
    const int dd  = t >> 2;     // d row 0..63
    const int seg = t & 3;      // 16-pos segment
    float msum = 0.f;
    unsigned int wv[8];
    #pragma unroll
    for (int i = 0; i < 8; ++i) {
        const int pos = seg * 16 + 2 * i;
        const int key = (pos & ~31) | ((pos & 4) << 2) | ((pos & 24) >> 1) | (pos & 3);
        const unsigned short s0 = (unsigned short)LV[key][dd];
        const unsigned short s1 = (unsigned short)LV[key + 1][dd];
        msum += bfu16_to_f(s0) + bfu16_to_f(s1);
        wv[i] = (unsigned int)s0 | ((unsigned int)s1 << 16);
    }
    msum += __shfl_xor(msum, 1);
    msum += __shfl_xor(msum, 2);
    if (seg == 0) atomicAdd(&MV[bh * DH + dd], msum * (1.0f / (float)SQ));

    if (k0 < el) {
        char* vbb = Vbt + (size_t)(bh * NTILE + kt) * TILE_B;
        const int fi  = (seg >> 1) * 4 + (dd >> 4);
        const int qd0 = (seg & 1) * 2;
        char* d0 = vbb + fi * 1024 + qd0 * 256 + (dd & 15) * 16;
        u32x4 o0 = {wv[0], wv[1], wv[2], wv[3]};
        u32x4 o1 = {wv[4], wv[5], wv[6], wv[7]};
        *(u32x4*)d0         = o0;
        *(u32x4*)(d0 + 256) = o1;
    }
}

// Main kernel: 512 threads = 8 waves x 32 queries = 256-q items.
// Per-XCD ticket queues (grp = blockIdx%8 over head%8), 3-ring counted vmcnt.
__global__ __launch_bounds__(512, 4)
void flash10(const float* __restrict__ Q, const int* __restrict__ EL,
             const float* __restrict__ MV, float* __restrict__ O,
             const char* __restrict__ Kbt, const char* __restrict__ Vbt,
             int* __restrict__ ticket) {
    const int t = threadIdx.x;

    // ---------- static phase: mean(V) rows for own fully-masked q-block ------
    {
        const int bh0 = blockIdx.x & (NBH - 1);
        const int qb0 = (blockIdx.x >> 6) * 256;     // grid 512: 8 chunks of 256q
        const int elb = EL[bh0 >> 4];
        if (qb0 >= elb) {
            float* Op = O + (size_t)bh0 * SQ * DH;
            const int c16 = t & 15, r0 = t >> 4;     // r0 0..31
            f32x4 mv = *(const f32x4*)(MV + bh0 * DH + c16 * 4);
            #pragma unroll
            for (int i = 0; i < 8; ++i)
                *(f32x4*)(Op + (size_t)(qb0 + r0 + i * 32) * DH + c16 * 4) = mv;
        }
    }

    // ---------- batch table, sorted descending by el (register network) ------
    int ka0 = EL[0], va0 = 0;
    int ka1 = EL[1], va1 = 1;
    int ka2 = EL[2], va2 = 2;
    int ka3 = EL[3], va3 = 3;
    #define CSWAP(x, y) if (ka##x < ka##y) { int tk_ = ka##x, tv_ = va##x; \
        ka##x = ka##y; va##x = va##y; ka##y = tk_; va##y = tv_; }
    CSWAP(0, 1) CSWAP(2, 3) CSWAP(0, 2) CSWAP(1, 3) CSWAP(1, 2)
    #undef CSWAP
    const int c0 = 2 * ((ka0 + 255) >> 8);   // items per (group, batch), sorted order
    const int c1 = 2 * ((ka1 + 255) >> 8);
    const int c2 = 2 * ((ka2 + 255) >> 8);
    const int c3 = 2 * ((ka3 + 255) >> 8);
    const int nvalid = c0 + c1 + c2 + c3;    // identical for every group

    __shared__ char KB[3 * TILE_B];
    __shared__ char VB[3 * TILE_B];
    __shared__ int item_s;

    const int grp = blockIdx.x & 7;          // blockIdx%8 ~ XCD (perf-only assumption)
    const int wq = t >> 6, lane = t & 63, qd = lane >> 4, c = lane & 15;
    const float sc = 0.125f * 1.44269504f;   // 1/sqrt(D) * log2(e)

    for (;;) {
        if (t == 0) item_s = atomicAdd(&ticket[grp], 1);
        __syncthreads();                     // broadcast + all waves done with LDS
        const int it = item_s;
        if (it >= nvalid) break;

        // decode (largest batch first)
        int u = it, b, el;
        if (u < c0)             { b = va0; el = ka0; }
        else { u -= c0;
        if (u < c1)             { b = va1; el = ka1; }
        else { u -= c1;
        if (u < c2)             { b = va2; el = ka2; }
        else { u -= c2;           b = va3; el = ka3; } } }
        const int vb_ = (el + 255) >> 8;
        const int hh  = u / vb_;
        const int qt  = u - hh * vb_;
        const int bh  = b * 16 + grp + hh * 8;   // head%8 == grp -> L2 affinity
        const int qbase = qt * 256;

        const float* Qp = Q + (size_t)bh * SQ * DH;
        float*       Op = O + (size_t)bh * SQ * DH;
        const char*  Kt = Kbt + (size_t)bh * NTILE * TILE_B + t * 16;
        const char*  Vt = Vbt + (size_t)bh * NTILE * TILE_B + t * 16;
        char* const  kdst = KB + wq * 1024;
        char* const  vdst = VB + wq * 1024;

        const int nkt = (el + TK - 1) >> 6;

        // prologue: tiles 0 and 1 in flight (2 VMEM instr per wave per tile)
        async_cp16(Kt, kdst);
        async_cp16(Vt, vdst);
        if (nkt > 1) {
            async_cp16(Kt + TILE_B, kdst + TILE_B);
            async_cp16(Vt + TILE_B, vdst + TILE_B);
        }

        // Q fragments (B-operand of S^T = K*Q^T); scale folded in
        bf16x8 qf[2][2];
        #pragma unroll
        for (int nt = 0; nt < 2; ++nt) {
            const int row = qbase + wq * 32 + nt * 16 + c;
            #pragma unroll
            for (int kc = 0; kc < 2; ++kc) {
                const float* p = Qp + (size_t)row * DH + kc * 32 + qd * 8;
                f32x4 a  = *(const f32x4*)p;
                f32x4 bq = *(const f32x4*)(p + 4);
                u32x4 f;
                f[0] = pk2(a[0] * sc, a[1] * sc);
                f[1] = pk2(a[2] * sc, a[3] * sc);
                f[2] = pk2(bq[0] * sc, bq[1] * sc);
                f[3] = pk2(bq[2] * sc, bq[3] * sc);
                qf[nt][kc] = *(bf16x8*)&f;
            }
        }

        float l_[2] = {0.f, 0.f};
        f32x4 oacc[4][2];
        #pragma unroll
        for (int dt = 0; dt < 4; ++dt) {
            oacc[dt][0] = (f32x4){0.f, 0.f, 0.f, 0.f};
            oacc[dt][1] = (f32x4){0.f, 0.f, 0.f, 0.f};
        }

        for (int kt = 0; kt < nkt; ++kt) {
            const int s = kt % 3;

            // all waves finished tile kt-1 -> its ring slot is reusable
            __syncthreads();
            if (kt + 2 < nkt) {
                const int s2 = (kt + 2) % 3;
                async_cp16(Kt + (size_t)(kt + 2) * TILE_B, kdst + s2 * TILE_B);
                async_cp16(Vt + (size_t)(kt + 2) * TILE_B, vdst + s2 * TILE_B);
            }
            // counted wait: own tile-kt copies done; 2 future tiles stay in flight
            if      (kt + 2 < nkt) VMCNT(4);
            else if (kt + 1 < nkt) VMCNT(2);
            else                   VMCNT(0);
            __syncthreads();                 // everyone's tile-kt lines visible

            const char* Kb = KB + s * TILE_B + lane * 16;
            const char* Vb = VB + s * TILE_B + lane * 16;

            // ---- S^T = K * Q^T : contiguous fragment-line reads ----
            f32x4 st[4][2];
            __builtin_amdgcn_s_setprio(1);
            #pragma unroll
            for (int mt = 0; mt < 4; ++mt) {
                bf16x8 a0 = *(const bf16x8*)(Kb + (mt * 2) * 1024);
                bf16x8 a1 = *(const bf16x8*)(Kb + (mt * 2 + 1) * 1024);
                #pragma unroll
                for (int nt = 0; nt < 2; ++nt) {
                    f32x4 acc = (f32x4){0.f, 0.f, 0.f, 0.f};
                    acc = __builtin_amdgcn_mfma_f32_16x16x32_bf16(a0, qf[nt][0], acc, 0, 0, 0);
                    acc = __builtin_amdgcn_mfma_f32_16x16x32_bf16(a1, qf[nt][1], acc, 0, 0, 0);
                    st[mt][nt] = acc;
                }
            }
            __builtin_amdgcn_s_setprio(0);

            const int k0 = kt * TK;
            if (k0 + TK > el) {    // straddling tile: mask invalid keys
                #pragma unroll
                for (int mt = 0; mt < 4; ++mt)
                    #pragma unroll
                    for (int r = 0; r < 4; ++r)
                        if (k0 + mt * 16 + qd * 4 + r >= el) {
                            st[mt][0][r] = -1e30f;
                            st[mt][1][r] = -1e30f;
                        }
            }

            // ---- p = exp2(s); pack in-register (pi order == lane's own keys) ----
            u32x4 pw[2][2];
            #pragma unroll
            for (int nt = 0; nt < 2; ++nt) {
                #pragma unroll
                for (int mt = 0; mt < 4; ++mt) {
                    const float p0 = __builtin_amdgcn_exp2f(st[mt][nt][0]);
                    const float p1 = __builtin_amdgcn_exp2f(st[mt][nt][1]);
                    const float p2 = __builtin_amdgcn_exp2f(st[mt][nt][2]);
                    const float p3 = __builtin_amdgcn_exp2f(st[mt][nt][3]);
                    l_[nt] += (p0 + p1) + (p2 + p3);
                    pw[nt][mt >> 1][(mt & 1) * 2]     = pk2(p0, p1);
                    pw[nt][mt >> 1][(mt & 1) * 2 + 1] = pk2(p2, p3);
                }
            }

            // ---- O^T += V^T * P^T : V lines pi-permuted, P in-register ----
            __builtin_amdgcn_s_setprio(1);
            #pragma unroll
            for (int kc = 0; kc < 2; ++kc) {
                bf16x8 pb0 = *(bf16x8*)&pw[0][kc];
                bf16x8 pb1 = *(bf16x8*)&pw[1][kc];
                #pragma unroll
                for (int dt = 0; dt < 4; ++dt) {
                    bf16x8 vf = *(const bf16x8*)(Vb + (kc * 4 + dt) * 1024);
                    oacc[dt][0] = __builtin_amdgcn_mfma_f32_16x16x32_bf16(vf, pb0, oacc[dt][0], 0, 0, 0);
                    oacc[dt][1] = __builtin_amdgcn_mfma_f32_16x16x32_bf16(vf, pb1, oacc[dt][1], 0, 0, 0);
                }
            }
            __builtin_amdgcn_s_setprio(0);
        }

        // denominators: cross-lane combine over qd groups (same query col c)
        #pragma unroll
        for (int nt = 0; nt < 2; ++nt) {
            l_[nt] += __shfl_xor(l_[nt], 16);
            l_[nt] += __shfl_xor(l_[nt], 32);
        }

        #pragma unroll
        for (int nt = 0; nt < 2; ++nt) {
            const int qrow = qbase + wq * 32 + nt * 16 + c;
            if (qrow < el) {
                const float inv = 1.0f / l_[nt];
                #pragma unroll
                for (int dt = 0; dt < 4; ++dt) {
                    f32x4 o = oacc[dt][nt];
                    o[0] *= inv; o[1] *= inv; o[2] *= inv; o[3] *= inv;
                    *(f32x4*)(Op + (size_t)qrow * DH + dt * 16 + qd * 4) = o;
                }
            } else {
                #pragma unroll
                for (int dt = 0; dt < 4; ++dt)
                    *(f32x4*)(Op + (size_t)qrow * DH + dt * 16 + qd * 4) =
                        *(const f32x4*)(MV + bh * DH + dt * 16 + qd * 4);
            }
        }
    }
}

// ============================================================================
// FALLBACK PATH (proven R5 kernels, used when ws_size < ~33.6 MB)
// ============================================================================

__global__ __launch_bounds__(256)
void meanv_k(const float* __restrict__ V, float* __restrict__ MV) {
    const int bh  = blockIdx.x >> 4;
    const int seg = blockIdx.x & 15;
    const float* vp = V + ((size_t)bh * SQ + (size_t)seg * 128) * DH;
    const int c = threadIdx.x & 15;
    const int r = threadIdx.x >> 4;
    const float* p = vp + (size_t)r * DH + c * 4;
    f32x4 s0 = *(const f32x4*)(p);
    f32x4 s1 = *(const f32x4*)(p + 16 * DH);
    f32x4 s2 = *(const f32x4*)(p + 32 * DH);
    f32x4 s3 = *(const f32x4*)(p + 48 * DH);
    s0 += *(const f32x4*)(p + 64 * DH);
    s1 += *(const f32x4*)(p + 80 * DH);
    s2 += *(const f32x4*)(p + 96 * DH);
    s3 += *(const f32x4*)(p + 112 * DH);
    f32x4 s = (s0 + s1) + (s2 + s3);
    __shared__ f32x4 red[16][16];
    red[r][c] = s;
    __syncthreads();
    if (threadIdx.x < 16) {
        f32x4 a = red[0][threadIdx.x];
        #pragma unroll
        for (int j = 1; j < 16; ++j) a += red[j][threadIdx.x];
        const float inv = 1.0f / (float)SQ;
        atomicAdd(&MV[bh * DH + threadIdx.x * 4 + 0], a[0] * inv);
        atomicAdd(&MV[bh * DH + threadIdx.x * 4 + 1], a[1] * inv);
        atomicAdd(&MV[bh * DH + threadIdx.x * 4 + 2], a[2] * inv);
        atomicAdd(&MV[bh * DH + threadIdx.x * 4 + 3], a[3] * inv);
    }
}

__global__ __launch_bounds__(256, 3)
void flash5(const float* __restrict__ Q, const float* __restrict__ K,
            const float* __restrict__ V, const int* __restrict__ EL,
            const float* __restrict__ MV, float* __restrict__ O,
            int* __restrict__ ticket) {
    const int t = threadIdx.x;
    {
        const int bh0    = blockIdx.x & (NBH - 1);
        const int qbase0 = (blockIdx.x >> 6) * 128;
        const int elb    = EL[bh0 >> 4];
        if (qbase0 >= elb) {
            float* Op = O + (size_t)bh0 * SQ * DH;
            const int c16 = t & 15, r0 = t >> 4;
            f32x4 mv = *(const f32x4*)(MV + bh0 * DH + c16 * 4);
            #pragma unroll
            for (int i = 0; i < 8; ++i)
                *(f32x4*)(Op + (size_t)(qbase0 + r0 + i * 16) * DH + c16 * 4) = mv;
        }
    }

    const int el0 = EL[0], el1 = EL[1], el2 = EL[2], el3 = EL[3];
    const int v0 = (el0 + 127) >> 7, v1 = (el1 + 127) >> 7;
    const int v2 = (el2 + 127) >> 7, v3 = (el3 + 127) >> 7;
    const int n0 = 16 * v0, n1 = n0 + 16 * v1, n2 = n1 + 16 * v2;
    const int nvalid = n2 + 16 * v3;

    __shared__ short Kb[TK][LDE];
    __shared__ short Vt[DH][LDE];
    __shared__ short Pl[4][32][LDE];
    __shared__ int item_s;

    const int wq = t >> 6, lane = t & 63, qd = lane >> 4, c = lane & 15;
    const int ksrow = t >> 2;
    const int ksdc  = t & 3;
    const int vpair = t & 31;
    const int vdg   = t >> 5;

    for (;;) {
        if (t == 0) item_s = atomicAdd(ticket, 1);
        __syncthreads();
        const int it = item_s;
        if (it >= nvalid) break;

        int b, u, vb, el;
        if      (it < n0) { b = 0; u = it;      vb = v0; el = el0; }
        else if (it < n1) { b = 1; u = it - n0; vb = v1; el = el1; }
        else if (it < n2) { b = 2; u = it - n1; vb = v2; el = el2; }
        else              { b = 3; u = it - n2; vb = v3; el = el3; }
        const int head  = u / vb;
        const int qt    = u - head * vb;
        const int bh    = b * 16 + head;
        const int qbase = qt * 128;

        const size_t base = (size_t)bh * SQ * DH;
        const float* Qp = Q + base;
        const float* Kp = K + base;
        const float* Vp = V + base;
        float* Op = O + base;

        const float sc = 0.125f * 1.44269504f;
        bf16x8 qf[2][2];
        #pragma unroll
        for (int nt = 0; nt < 2; ++nt) {
            const int row = qbase + wq * 32 + nt * 16 + c;
            #pragma unroll
            for (int kc = 0; kc < 2; ++kc) {
                const float* p = Qp + (size_t)row * DH + kc * 32 + qd * 8;
                f32x4 a  = *(const f32x4*)p;
                f32x4 bb = *(const f32x4*)(p + 4);
                u32x4 f;
                f[0] = pk2(a[0] * sc, a[1] * sc);
                f[1] = pk2(a[2] * sc, a[3] * sc);
                f[2] = pk2(bb[0] * sc, bb[1] * sc);
                f[3] = pk2(bb[2] * sc, bb[3] * sc);
                qf[nt][kc] = *(bf16x8*)&f;
            }
        }

        float l_[2] = {0.f, 0.f};
        f32x4 oacc[4][2];
        #pragma unroll
        for (int dt = 0; dt < 4; ++dt)
            #pragma unroll
            for (int nt = 0; nt < 2; ++nt)
                oacc[dt][nt] = (f32x4){0.f, 0.f, 0.f, 0.f};

        const int nkt = (el + TK - 1) / TK;

        f32x4 kg0, kg1, kg2, kg3, vg0, vg1, vg2, vg3;
        {
            const float* kp = Kp + (size_t)ksrow * DH + ksdc * 16;
            kg0 = *(const f32x4*)kp;
            kg1 = *(const f32x4*)(kp + 4);
            kg2 = *(const f32x4*)(kp + 8);
            kg3 = *(const f32x4*)(kp + 12);
            const float* vp0 = Vp + (size_t)(2 * vpair) * DH + vdg * 8;
            vg0 = *(const f32x4*)vp0;
            vg1 = *(const f32x4*)(vp0 + 4);
            vg2 = *(const f32x4*)(vp0 + DH);
            vg3 = *(const f32x4*)(vp0 + DH + 4);
        }

        for (int kt = 0; kt < nkt; ++kt) {
            const int k0 = kt * TK;

            __syncthreads();
            {
                u32x4 w0, w1;
                w0[0] = pk2(kg0[0], kg0[1]); w0[1] = pk2(kg0[2], kg0[3]);
                w0[2] = pk2(kg1[0], kg1[1]); w0[3] = pk2(kg1[2], kg1[3]);
                w1[0] = pk2(kg2[0], kg2[1]); w1[1] = pk2(kg2[2], kg2[3]);
                w1[2] = pk2(kg3[0], kg3[1]); w1[3] = pk2(kg3[2], kg3[3]);
                *(u32x4*)&Kb[ksrow][ksdc * 16]     = w0;
                *(u32x4*)&Kb[ksrow][ksdc * 16 + 8] = w1;
            }
            {
                #pragma unroll
                for (int i = 0; i < 4; ++i) {
                    *(unsigned int*)&Vt[vdg * 8 + i][2 * vpair]     = pk2(vg0[i], vg2[i]);
                    *(unsigned int*)&Vt[vdg * 8 + 4 + i][2 * vpair] = pk2(vg1[i], vg3[i]);
                }
            }
            __syncthreads();

            if (kt + 1 < nkt) {
                const int kn = k0 + TK;
                const float* kp = Kp + (size_t)(kn + ksrow) * DH + ksdc * 16;
                kg0 = *(const f32x4*)kp;
                kg1 = *(const f32x4*)(kp + 4);
                kg2 = *(const f32x4*)(kp + 8);
                kg3 = *(const f32x4*)(kp + 12);
                const float* vp0 = Vp + (size_t)(kn + 2 * vpair) * DH + vdg * 8;
                vg0 = *(const f32x4*)vp0;
                vg1 = *(const f32x4*)(vp0 + 4);
                vg2 = *(const f32x4*)(vp0 + DH);
                vg3 = *(const f32x4*)(vp0 + DH + 4);
            }

            f32x4 st[4][2];
            #pragma unroll
            for (int mt = 0; mt < 4; ++mt) {
                bf16x8 a0 = *(const bf16x8*)&Kb[mt * 16 + c][qd * 8];
                bf16x8 a1 = *(const bf16x8*)&Kb[mt * 16 + c][32 + qd * 8];
                #pragma unroll
                for (int nt = 0; nt < 2; ++nt) {
                    f32x4 acc = (f32x4){0.f, 0.f, 0.f, 0.f};
                    acc = __builtin_amdgcn_mfma_f32_16x16x32_bf16(a0, qf[nt][0], acc, 0, 0, 0);
                    acc = __builtin_amdgcn_mfma_f32_16x16x32_bf16(a1, qf[nt][1], acc, 0, 0, 0);
                    st[mt][nt] = acc;
                }
            }

            if (k0 + TK > el) {
                #pragma unroll
                for (int mt = 0; mt < 4; ++mt)
                    #pragma unroll
                    for (int r = 0; r < 4; ++r)
                        if (k0 + mt * 16 + qd * 4 + r >= el) {
                            st[mt][0][r] = -1e30f;
                            st[mt][1][r] = -1e30f;
                        }
            }

            #pragma unroll
            for (int nt = 0; nt < 2; ++nt) {
                #pragma unroll
                for (int mt = 0; mt < 4; ++mt) {
                    const float p0 = exp2f(st[mt][nt][0]);
                    const float p1 = exp2f(st[mt][nt][1]);
                    const float p2 = exp2f(st[mt][nt][2]);
                    const float p3 = exp2f(st[mt][nt][3]);
                    l_[nt] += (p0 + p1) + (p2 + p3);
                    u32x2 pw;
                    pw[0] = pk2(p0, p1);
                    pw[1] = pk2(p2, p3);
                    *(u32x2*)&Pl[wq][nt * 16 + c][mt * 16 + qd * 4] = pw;
                }
            }

            #pragma unroll
            for (int kc = 0; kc < 2; ++kc) {
                bf16x8 pb0 = *(const bf16x8*)&Pl[wq][c][kc * 32 + qd * 8];
                bf16x8 pb1 = *(const bf16x8*)&Pl[wq][16 + c][kc * 32 + qd * 8];
                #pragma unroll
                for (int dt = 0; dt < 4; ++dt) {
                    bf16x8 vf = *(const bf16x8*)&Vt[dt * 16 + c][kc * 32 + qd * 8];
                    oacc[dt][0] = __builtin_amdgcn_mfma_f32_16x16x32_bf16(vf, pb0, oacc[dt][0], 0, 0, 0);
                    oacc[dt][1] = __builtin_amdgcn_mfma_f32_16x16x32_bf16(vf, pb1, oacc[dt][1], 0, 0, 0);
                }
            }
        }

        #pragma unroll
        for (int nt = 0; nt < 2; ++nt) {
            l_[nt] += __shfl_xor(l_[nt], 16);
            l_[nt] += __shfl_xor(l_[nt], 32);
        }

        #pragma unroll
        for (int nt = 0; nt < 2; ++nt) {
            const int row = qbase + wq * 32 + nt * 16 + c;
            if (row < el) {
                const float inv = 1.0f / l_[nt];
                #pragma unroll
                for (int dt = 0; dt < 4; ++dt) {
                    f32x4 o = oacc[dt][nt];
                    o[0] *= inv; o[1] *= inv; o[2] *= inv; o[3] *= inv;
                    *(f32x4*)(Op + (size_t)row * DH + dt * 16 + qd * 4) = o;
                }
            } else {
                #pragma unroll
                for (int dt = 0; dt < 4; ++dt) {
                    f32x4 mv = *(const f32x4*)(MV + bh * DH + dt * 16 + qd * 4);
                    *(f32x4*)(Op + (size_t)row * DH + dt * 16 + qd * 4) = mv;
                }
            }
        }
    }
}

// ============================================================================

extern "C" void kernel_launch(void* const* d_in, const int* in_sizes, int n_in,
                              void* d_out, int out_size, void* d_ws, size_t ws_size,
                              hipStream_t stream) {
    const float* q  = (const float*)d_in[0];
    const float* k  = (const float*)d_in[1];
    const float* v  = (const float*)d_in[2];
    const int*   el = (const int*)d_in[3];
    float* out = (float*)d_out;

    const size_t kbt_bytes = (size_t)NBH * NTILE * TILE_B;      // 16 MiB
    const size_t needed    = 65536 + 2 * kbt_bytes;             // ~33.6 MiB

    if (ws_size >= needed) {
        // new path: fragment-ordered prepass + XCD-affinity-queue flash
        float* mv  = (float*)d_ws;
        int*   tk  = (int*)((char*)d_ws + 16384);               // 8 group tickets
        char*  kbt = (char*)d_ws + 65536;
        char*  vbt = kbt + kbt_bytes;

        hipMemsetAsync(d_ws, 0, 65536, stream);
        convkv<<<dim3(NBH * NTILE), dim3(256), 0, stream>>>(k, v, el, mv, kbt, vbt);
        flash10<<<dim3(NBH * (SQ / 256)), dim3(512), 0, stream>>>(q, el, mv, out, kbt, vbt, tk);
    } else {
        // fallback: proven R5 path
        float* mv = (float*)d_ws;
        int*   tk = (int*)((char*)d_ws + NBH * DH * sizeof(float));

        hipMemsetAsync(d_ws, 0, NBH * DH * sizeof(float) + 64, stream);
        meanv_k<<<dim3(NBH * 16), dim3(256), 0, stream>>>(v, mv);
        flash5<<<dim3(NBH * (SQ / 128)), dim3(256), 0, stream>>>(q, k, v, el, mv, out, tk);
    }
}